// Round 2
// baseline (113.751 us; speedup 1.0000x reference)
//
#include <hip/hip_runtime.h>

// GraphSAGE fused forward (live path only — neighbors_2/W1 branch is dead code
// w.r.t. the returned softmax, so we skip the 512MB 2-hop gather entirely).
//
// Inputs (setup_inputs order):
//   d_in[0] nodes        int32  [4096]
//   d_in[1] neighbors_1  int32  [4096,16]
//   d_in[2] neighbors_2  int32  [65536,16]   (UNUSED — dead code)
//   d_in[3] node_features f32   [100000,128]
//   d_in[4] W1           f32    [128,256]    (UNUSED — dead code)
//   d_in[5] W2           f32    [128,256]
//   d_in[6] Wo           f32    [64,128]
// Output: softmax(relu(cat[feat, mean_neigh] @ W2^T) @ Wo^T)  f32 [4096,64]

constexpr int D = 128;   // feature dim
constexpr int H = 128;   // hidden
constexpr int O = 64;    // classes
constexpr int S = 16;    // fan-out
constexpr int NB = 4096; // batch
constexpr int SPB = 8;   // seeds per block
constexpr int THREADS = 256;

__global__ __launch_bounds__(THREADS, 2) void sage_fused(
    const int* __restrict__ nodes,
    const int* __restrict__ neighbors_1,
    const float* __restrict__ node_features,
    const float* __restrict__ W2,
    const float* __restrict__ Wo,
    float* __restrict__ out)
{
    __shared__ float cat[SPB][2 * D];        // [origin | mean]  8 KB
    __shared__ float part[THREADS][SPB + 1]; // padded: stride 9 words, conflict-free
    __shared__ float h[SPB][H];              // 4 KB
    __shared__ int   nbs[SPB][S];
    __shared__ int   sid[SPB];

    const int t = threadIdx.x;
    const int seed0 = blockIdx.x * SPB;

    if (t < SPB) sid[t] = nodes[seed0 + t];
    if (t < SPB * S) nbs[t / S][t % S] = neighbors_1[seed0 * S + t];
    __syncthreads();

    // ---- gather (float4-vectorized): one seed per 32-lane group.
    // cat[r][0:128] = feat(origin), cat[r][128:256] = mean over 16 neighbors.
    {
        const int d4 = t & 31;              // float4 column 0..31 (covers 128 floats)
        const int r  = t >> 5;              // seed 0..7
        const float4* nf = reinterpret_cast<const float4*>(node_features);
        float4 sum = make_float4(0.f, 0.f, 0.f, 0.f);
        #pragma unroll
        for (int s = 0; s < S; ++s) {
            const float4 v = nf[(size_t)nbs[r][s] * (D / 4) + d4];
            sum.x += v.x; sum.y += v.y; sum.z += v.z; sum.w += v.w;
        }
        const float4 org = nf[(size_t)sid[r] * (D / 4) + d4];
        *reinterpret_cast<float4*>(&cat[r][4 * d4]) = org;
        const float4 mean = make_float4(sum.x * (1.f / 16.f), sum.y * (1.f / 16.f),
                                        sum.z * (1.f / 16.f), sum.w * (1.f / 16.f));
        *reinterpret_cast<float4*>(&cat[r][D + 4 * d4]) = mean;
    }
    __syncthreads();

    // ---- layer 2: h[r][j] = relu(sum_k cat[r][k] * W2[j][k]), k split in halves.
    // cat reads are wave-uniform (LDS broadcast, free); W2 reads are L1-resident
    // after the first k-sweep (8 KB live line window).
    {
        const int j = t & (H - 1);
        const int half = t >> 7;            // which 128-wide half of k
        const float* w = W2 + (size_t)j * (2 * D) + half * D;
        const float* c0 = &cat[0][half * D];
        float acc[SPB];
        #pragma unroll
        for (int r = 0; r < SPB; ++r) acc[r] = 0.f;
        for (int k = 0; k < D; k += 4) {
            const float4 wv = *reinterpret_cast<const float4*>(w + k);
            #pragma unroll
            for (int r = 0; r < SPB; ++r) {
                const float* c = c0 + r * (2 * D) + k;  // uniform addr → broadcast
                acc[r] = fmaf(wv.x, c[0], acc[r]);
                acc[r] = fmaf(wv.y, c[1], acc[r]);
                acc[r] = fmaf(wv.z, c[2], acc[r]);
                acc[r] = fmaf(wv.w, c[3], acc[r]);
            }
        }
        #pragma unroll
        for (int r = 0; r < SPB; ++r) part[t][r] = acc[r];
    }
    __syncthreads();

    // combine the two k-halves + relu
    for (int i = t; i < SPB * H; i += THREADS) {
        const int r = i >> 7;
        const int j = i & (H - 1);
        const float v = part[j][r] + part[j + H][r];
        h[r][j] = v > 0.f ? v : 0.f;
    }
    __syncthreads();

    // ---- output layer + softmax: one 64-lane wave-half... one wave per seed pair
    // (O=64 lanes = one full wave per seed iteration).
    {
        const int lane = t & 63;
        const int wv_id = t >> 6;           // wave 0..3
        const float* wo = Wo + (size_t)lane * H;
        for (int r = wv_id; r < SPB; r += 4) {
            float acc = 0.f;
            #pragma unroll
            for (int k = 0; k < H; k += 4) {
                const float4 wv = *reinterpret_cast<const float4*>(wo + k);
                acc = fmaf(wv.x, h[r][k + 0], acc);
                acc = fmaf(wv.y, h[r][k + 1], acc);
                acc = fmaf(wv.z, h[r][k + 2], acc);
                acc = fmaf(wv.w, h[r][k + 3], acc);
            }
            float m = acc;
            #pragma unroll
            for (int off = 32; off >= 1; off >>= 1)
                m = fmaxf(m, __shfl_xor(m, off));
            const float e = __expf(acc - m);
            float ssum = e;
            #pragma unroll
            for (int off = 32; off >= 1; off >>= 1)
                ssum += __shfl_xor(ssum, off);
            out[(size_t)(seed0 + r) * O + lane] = e / ssum;
        }
    }
}

extern "C" void kernel_launch(void* const* d_in, const int* in_sizes, int n_in,
                              void* d_out, int out_size, void* d_ws, size_t ws_size,
                              hipStream_t stream) {
    const int*   nodes         = (const int*)d_in[0];
    const int*   neighbors_1   = (const int*)d_in[1];
    // d_in[2] neighbors_2, d_in[4] W1: dead w.r.t. the output — skipped.
    const float* node_features = (const float*)d_in[3];
    const float* W2            = (const float*)d_in[5];
    const float* Wo            = (const float*)d_in[6];
    float*       out           = (float*)d_out;

    sage_fused<<<NB / SPB, THREADS, 0, stream>>>(
        nodes, neighbors_1, node_features, W2, Wo, out);
}